// Round 1
// baseline (178.260 us; speedup 1.0000x reference)
//
#include <hip/hip_runtime.h>

// RoutingBlock: per-batch argmax over 4 routing logits selects a 128-channel
// slice of the 512-channel input. Output (64,32,32,128) fp32.
//
// Layout constants:
//   B=64, H=32, W=32, C=512, ROUTES=4, RW=128
//   out float4 per batch  = 32*32*128/4 = 32768  (divisible by 256 -> b uniform per block)
//   in  float4 per pixel  = 512/4 = 128
//   out float4 per pixel  = 128/4 = 32

__global__ __launch_bounds__(256) void routing_gather_kernel(
    const float4* __restrict__ in,      // B*H*W*512 floats as float4
    const float*  __restrict__ rx,      // B*4 routing logits
    float4*       __restrict__ out)     // B*H*W*128 floats as float4
{
    const int i = blockIdx.x * 256 + threadIdx.x;   // out float4 index
    const int b = i >> 15;                          // / 32768 (block-uniform)

    __shared__ int s_route;
    if (threadIdx.x == 0) {
        const float* r = rx + (b << 2);
        float v0 = r[0], v1 = r[1], v2 = r[2], v3 = r[3];
        int idx = 0; float mv = v0;
        if (v1 > mv) { mv = v1; idx = 1; }   // strict > keeps first-occurrence
        if (v2 > mv) { mv = v2; idx = 2; }   // semantics, matching jnp.argmax
        if (v3 > mv) { mv = v3; idx = 3; }
        s_route = idx;
    }
    __syncthreads();
    const int route = s_route;

    const int within = i & 32767;        // out float4 within batch
    const int s      = within >> 5;      // pixel index within batch (0..1023)
    const int c4     = within & 31;      // float4 within the 128-ch slice

    // input float4 index: ((b*1024 + s) * 128) + route*32 + c4
    const int in_idx = (((b << 10) + s) << 7) + (route << 5) + c4;

    out[i] = in[in_idx];
}

extern "C" void kernel_launch(void* const* d_in, const int* in_sizes, int n_in,
                              void* d_out, int out_size, void* d_ws, size_t ws_size,
                              hipStream_t stream) {
    const float4* in  = (const float4*)d_in[0];   // inputs  (64,32,32,512) fp32
    const float*  rx  = (const float*)d_in[1];    // routing_x (64,4) fp32
    float4*       out = (float4*)d_out;           // (64,32,32,128) fp32

    // 2,097,152 out float4 / 256 threads = 8192 blocks
    routing_gather_kernel<<<8192, 256, 0, stream>>>(in, rx, out);
}